// Round 17
// baseline (118.048 us; speedup 1.0000x reference)
//
#include <hip/hip_runtime.h>
#include <hip/hip_bf16.h>
#include <cstdint>

#define DEV static __device__ __forceinline__

typedef unsigned short u16t;
typedef __attribute__((ext_vector_type(4))) float f32x4;
typedef __attribute__((ext_vector_type(4))) unsigned short u16x4;
typedef __attribute__((ext_vector_type(8))) unsigned short u16x8;
typedef __attribute__((ext_vector_type(8))) __bf16 bf16x8;

DEV u16t f2bf(float f) {
  unsigned u = __builtin_bit_cast(unsigned, f);
  u += 0x7fffu + ((u >> 16) & 1u);
  return (u16t)(u >> 16);
}
DEV float bf2f(u16t h) {
  unsigned u = ((unsigned)h) << 16;
  return __builtin_bit_cast(float, u);
}

DEV void gload_lds16(const void* g, void* l) {
  __builtin_amdgcn_global_load_lds(
      (const __attribute__((address_space(1))) void*)g,
      (__attribute__((address_space(3))) void*)l, 16, 0, 0);
}

DEV bf16x8 ldsfrag(const u16t* p) {
  return __builtin_bit_cast(bf16x8, *(const u16x8*)p);
}

// raw workgroup barrier WITHOUT __syncthreads' implicit vmcnt(0) drain
DEV void bsync() {
  asm volatile("" ::: "memory");
  __builtin_amdgcn_s_barrier();
  asm volatile("" ::: "memory");
}

// ---------------- convert x (fp32 -> bf16) ----------------
__global__ __launch_bounds__(256) void k_convert_x(const float* __restrict__ x,
                                                   u16t* __restrict__ xb) {
  int i = (blockIdx.x * 256 + threadIdx.x) * 4;
  f32x4 v = *(const f32x4*)&x[i];
  u16x4 o;
#pragma unroll
  for (int j = 0; j < 4; ++j) o[j] = f2bf(v[j]);
  *(u16x4*)&xb[i] = o;
}

// ------------- transpose + convert weights (fp32 [K][N] -> bf16 [N][K]) -------------
__global__ __launch_bounds__(256) void k_transw(const float* __restrict__ w0,
                                                const float* __restrict__ w1,
                                                const float* __restrict__ w2,
                                                const float* __restrict__ w3,
                                                u16t* __restrict__ qkvT,
                                                u16t* __restrict__ oT) {
  __shared__ float lds[64][68];
  int z = blockIdx.z;
  const float* W = (z == 0) ? w0 : (z == 1) ? w1 : (z == 2) ? w2 : w3;
  u16t* OUT = (z < 3) ? (qkvT + (size_t)z * 1024 * 1024) : oT;
  int k0 = blockIdx.x * 64, n0 = blockIdx.y * 64;
  int t = threadIdx.x;
  int kl = t >> 4, n4 = (t & 15) << 2;
#pragma unroll
  for (int p = 0; p < 4; ++p) {
    f32x4 v = *(const f32x4*)&W[(size_t)(k0 + kl + p * 16) * 1024 + n0 + n4];
    *(f32x4*)&lds[kl + p * 16][n4] = v;
  }
  __syncthreads();
  int nl = t >> 4, k4 = (t & 15) << 2;
#pragma unroll
  for (int p = 0; p < 4; ++p) {
    int n = nl + p * 16;
    u16x4 o;
#pragma unroll
    for (int i = 0; i < 4; ++i) o[i] = f2bf(lds[k4 + i][n]);
    *(u16x4*)&OUT[(size_t)(n0 + n) * 1024 + k0 + k4] = o;
  }
}

// ---------------- GEMM: C[M,N] = A[M,K] * BT[N,K]^T + bias ----------------
// m-tile = MI*32 rows, n-tile = 128. SINGLE-buffered (24KB LDS for MI=2) so all
// 6 launched blocks/CU stay resident; the per-iter vmcnt(0) drain is hidden by
// sibling chains (r10/r12-proven pattern). VSPLIT: cols >= 2048 written
// transposed into vt[bh][d][s].
template <int MI, bool BF16_OUT, bool VSPLIT>
__global__ __launch_bounds__(256) void k_gemm_bt(const u16t* __restrict__ A,
                                                 const u16t* __restrict__ BT,
                                                 void* __restrict__ Cout,
                                                 const float* __restrict__ b0,
                                                 const float* __restrict__ b1,
                                                 const float* __restrict__ b2,
                                                 u16t* __restrict__ vt,
                                                 int M, int N, int K) {
  __shared__ u16t Al[MI * 32 * 64];
  __shared__ u16t Bl[128 * 64];
  const int tid = threadIdx.x;
  const int l = tid & 63;
  const int w = tid >> 6;
  const int m0 = blockIdx.x * (MI * 32), n0 = blockIdx.y * 128;
  const int wm = (w >> 1) * (MI * 16), wn = (w & 1) * 64;
  const int lm = l & 15, lh = l >> 4;
  f32x4 acc[MI][4] = {};

  const int nt = K >> 6;
  for (int t = 0; t < nt; ++t) {
    const int k0 = t << 6;
#pragma unroll
    for (int s = 0; s < MI; ++s) {
      int c = s * 256 + tid;
      int row = c >> 3, slot = c & 7;
      int ks = k0 + (((slot ^ (row & 7)) & 7) << 3);
      gload_lds16(A + (size_t)(m0 + row) * K + ks, &Al[c * 8]);
    }
#pragma unroll
    for (int s = 0; s < 4; ++s) {
      int c = s * 256 + tid;
      int row = c >> 3, slot = c & 7;
      int ks = k0 + (((slot ^ (row & 7)) & 7) << 3);
      gload_lds16(BT + (size_t)(n0 + row) * K + ks, &Bl[c * 8]);
    }
    asm volatile("s_waitcnt vmcnt(0)" ::: "memory");
    bsync();

#pragma unroll
    for (int kk = 0; kk < 2; ++kk) {
      bf16x8 af[MI], bfr[4];
#pragma unroll
      for (int i = 0; i < MI; ++i) {
        int ra = wm + i * 16 + lm;
        int sa = (kk * 4 + lh) ^ (ra & 7);
        af[i] = ldsfrag(&Al[ra * 64 + sa * 8]);
      }
#pragma unroll
      for (int i = 0; i < 4; ++i) {
        int rb = wn + i * 16 + lm;
        int sb = (kk * 4 + lh) ^ (rb & 7);
        bfr[i] = ldsfrag(&Bl[rb * 64 + sb * 8]);
      }
      __builtin_amdgcn_s_setprio(1);
#pragma unroll
      for (int i = 0; i < MI; ++i)
#pragma unroll
        for (int j = 0; j < 4; ++j)
          acc[i][j] = __builtin_amdgcn_mfma_f32_16x16x32_bf16(af[i], bfr[j],
                                                              acc[i][j], 0, 0, 0);
      __builtin_amdgcn_s_setprio(0);
    }
    bsync();
  }

  if (!VSPLIT || (n0 + wn) < 2048) {
#pragma unroll
    for (int i = 0; i < MI; ++i) {
      int row = m0 + wm + i * 16 + (lh << 2);
#pragma unroll
      for (int j = 0; j < 4; ++j) {
        int col = n0 + wn + j * 16 + lm;
        const float* bp = (col < 1024) ? b0 : ((col < 2048) ? b1 : b2);
        float bias = bp[col & 1023];
#pragma unroll
        for (int r = 0; r < 4; ++r) {
          float v = acc[i][j][r] + bias;
          if (BF16_OUT)
            ((u16t*)Cout)[(size_t)(row + r) * N + col] = f2bf(v);
          else
            ((float*)Cout)[(size_t)(row + r) * N + col] = v;
        }
      }
    }
  } else {
    // V projection: write transposed to vt[(b*16+h)*64 + d][s]
#pragma unroll
    for (int i = 0; i < MI; ++i) {
      int row = m0 + wm + i * 16 + (lh << 2);
      int bidx = row >> 11, s0 = row & 2047;
#pragma unroll
      for (int j = 0; j < 4; ++j) {
        int col = n0 + wn + j * 16 + lm;
        int d = col - 2048;
        int hh = d >> 6, dd = d & 63;
        float bias = b2[d];
        u16x4 o;
#pragma unroll
        for (int r = 0; r < 4; ++r) o[r] = f2bf(acc[i][j][r] + bias);
        *(u16x4*)&vt[((size_t)((bidx * 16 + hh) * 64 + dd)) * 2048 + s0] = o;
      }
    }
  }
}

// ---------------- causal flash attention (split-KV + 32 q-rows/wave, r14-proven) ----------------
__global__ __launch_bounds__(256, 2) void k_attn(const u16t* qkv,
                                                 const u16t* __restrict__ vt,
                                                 u16t* __restrict__ outp,
                                                 u16t* scratch) {
  __shared__ u16t Kl[4096];        // [kv=64][d=64], 16B-slot swizzled
  __shared__ u16t Vl[4096];        // [d=64][kv=64], 16B-slot swizzled
  __shared__ u16t Pl[4][2][1024];  // [wave][qm][q=16][kv=64], swizzled
  const int tid = threadIdx.x, l = tid & 63, w = tid >> 6;
  const int lm = l & 15, lh = l >> 4;
  const int bh = blockIdx.x, b = bh >> 4, h = bh & 15;
  const int y = blockIdx.y;
  const int zone = y >> 3, j = y & 7;
  const int qt = (zone == 0) ? j : (15 - j);  // 128-row q-tile index
  const int q0 = qt * 128;
  const int halfn = qt + 1;
  const int t0 = (zone == 2) ? halfn : 0;
  const int t1 = (zone == 1) ? halfn : (2 * qt + 2);
  const int qbase = q0 + w * 32;

  // Q fragments (B-operand), pre-scaled by (1/sqrt(64))*log2(e) -> exp2 softmax
  bf16x8 aq[2][2];
#pragma unroll
  for (int qm = 0; qm < 2; ++qm)
#pragma unroll
    for (int kk = 0; kk < 2; ++kk) {
      const u16t* src = qkv + (size_t)(b * 2048 + qbase + qm * 16 + lm) * 3072 +
                        h * 64 + kk * 32 + lh * 8;
      u16x8 v = *(const u16x8*)src;
      u16x8 o;
#pragma unroll
      for (int e = 0; e < 8; ++e) o[e] = f2bf(bf2f(v[e]) * 0.1803368801f);
      aq[qm][kk] = __builtin_bit_cast(bf16x8, o);
    }

  float lsum[2] = {0.f, 0.f};
  f32x4 aco[2][4] = {};
  const int qr0 = qbase + lm, qr1 = qbase + 16 + lm;

  const u16t* Kg = qkv + (size_t)b * 2048 * 3072 + 1024 + h * 64;
  const u16t* Vg = vt + (size_t)bh * 64 * 2048;

  auto stage = [&](int t) {
#pragma unroll
    for (int s = 0; s < 2; ++s) {
      int c = s * 256 + tid;
      int row = c >> 3, col = ((c & 7) ^ (row & 7)) << 3;
      gload_lds16(Kg + (size_t)(t * 64 + row) * 3072 + col, &Kl[c * 8]);
    }
#pragma unroll
    for (int s = 0; s < 2; ++s) {
      int c = s * 256 + tid;
      int row = c >> 3, col = ((c & 7) ^ (row & 7)) << 3;
      gload_lds16(Vg + (size_t)row * 2048 + t * 64 + col, &Vl[c * 8]);
    }
  };

  for (int t = t0; t < t1; ++t) {
    stage(t);
    asm volatile("s_waitcnt vmcnt(0)" ::: "memory");
    bsync();

    // wave-uniform: skip fully-masked diagonal tiles (kv all > every q-row)
    if (t * 64 <= qbase + 31) {
      // S^T = K * Q
      f32x4 accs[2][4] = {};
#pragma unroll
      for (int kk = 0; kk < 2; ++kk) {
        bf16x8 ak[4];
#pragma unroll
        for (int nk = 0; nk < 4; ++nk) {
          int rk = nk * 16 + lm;
          int s16 = (kk * 4 + lh) ^ (rk & 7);
          ak[nk] = ldsfrag(&Kl[rk * 64 + s16 * 8]);
        }
        __builtin_amdgcn_s_setprio(1);
#pragma unroll
        for (int nk = 0; nk < 4; ++nk) {
          accs[0][nk] = __builtin_amdgcn_mfma_f32_16x16x32_bf16(
              ak[nk], aq[0][kk], accs[0][nk], 0, 0, 0);
          accs[1][nk] = __builtin_amdgcn_mfma_f32_16x16x32_bf16(
              ak[nk], aq[1][kk], accs[1][nk], 0, 0, 0);
        }
        __builtin_amdgcn_s_setprio(0);
      }

      // causal mask only when this wave's rows touch the diagonal (wave-uniform)
      if (t * 64 + 63 > qbase) {
#pragma unroll
        for (int nk = 0; nk < 4; ++nk)
#pragma unroll
          for (int r = 0; r < 4; ++r) {
            int kvpos = t * 64 + nk * 16 + lh * 4 + r;
            if (kvpos > qr0) accs[0][nk][r] = -1e30f;
            if (kvpos > qr1) accs[1][nk][r] = -1e30f;
          }
      }

      // p = exp2(s'); partial lsum; cvt_pk pack -> b64 store to P-LDS
#pragma unroll
      for (int qm = 0; qm < 2; ++qm) {
        u16t* Pw = &Pl[w][qm][0];
#pragma unroll
        for (int nk = 0; nk < 4; ++nk) {
          float p0 = exp2f(accs[qm][nk][0]);
          float p1 = exp2f(accs[qm][nk][1]);
          float p2 = exp2f(accs[qm][nk][2]);
          float p3 = exp2f(accs[qm][nk][3]);
          lsum[qm] += (p0 + p1) + (p2 + p3);
          unsigned wlo, whi;
          asm("v_cvt_pk_bf16_f32 %0, %1, %2" : "=v"(wlo) : "v"(p0), "v"(p1));
          asm("v_cvt_pk_bf16_f32 %0, %1, %2" : "=v"(whi) : "v"(p2), "v"(p3));
          int off = lm * 64 + ((((2 * nk + (lh >> 1)) ^ (lm & 7)) & 7) << 3) +
                    ((lh & 1) << 2);
          *(uint2*)&Pw[off] = make_uint2(wlo, whi);
        }
      }

      // O += P * V
#pragma unroll
      for (int kk = 0; kk < 2; ++kk) {
        int sp = (kk * 4 + lh) ^ (lm & 7);
        bf16x8 ap0 = ldsfrag(&Pl[w][0][lm * 64 + sp * 8]);
        bf16x8 ap1 = ldsfrag(&Pl[w][1][lm * 64 + sp * 8]);
        __builtin_amdgcn_s_setprio(1);
#pragma unroll
        for (int nd = 0; nd < 4; ++nd) {
          int rv = nd * 16 + lm;
          int sv = (kk * 4 + lh) ^ (rv & 7);
          bf16x8 bv = ldsfrag(&Vl[rv * 64 + sv * 8]);
          aco[0][nd] =
              __builtin_amdgcn_mfma_f32_16x16x32_bf16(ap0, bv, aco[0][nd], 0, 0, 0);
          aco[1][nd] =
              __builtin_amdgcn_mfma_f32_16x16x32_bf16(ap1, bv, aco[1][nd], 0, 0, 0);
        }
        __builtin_amdgcn_s_setprio(0);
      }
    }

    bsync();
  }

  // epilogue: finish lsum reduce over lh groups
#pragma unroll
  for (int qm = 0; qm < 2; ++qm) {
    lsum[qm] += __shfl_xor(lsum[qm], 16);
    lsum[qm] += __shfl_xor(lsum[qm], 32);
  }

  if (zone == 0) {
#pragma unroll
    for (int qm = 0; qm < 2; ++qm) {
      float inv = 1.0f / lsum[qm];
#pragma unroll
      for (int r = 0; r < 4; ++r) {
        float ir = __shfl(inv, lh * 4 + r);
        int row = qbase + qm * 16 + lh * 4 + r;
#pragma unroll
        for (int nd = 0; nd < 4; ++nd) {
          int col = h * 64 + nd * 16 + lm;
          outp[(size_t)(b * 2048 + row) * 1024 + col] = f2bf(aco[qm][nd][r] * ir);
        }
      }
    }
  } else {
    // store unnormalized partial O (bf16)
#pragma unroll
    for (int qm = 0; qm < 2; ++qm)
#pragma unroll
      for (int r = 0; r < 4; ++r) {
        int row = qbase + qm * 16 + lh * 4 + r;
#pragma unroll
        for (int nd = 0; nd < 4; ++nd) {
          int col = nd * 16 + lm;
          u16t v = f2bf(aco[qm][nd][r]);
          if (zone == 1)
            outp[(size_t)(b * 2048 + row) * 1024 + h * 64 + col] = v;
          else
            scratch[(size_t)(b * 2048 + row - 1024) * 3072 + 2048 + h * 64 + col] = v;
        }
      }
    // store partial l (f32) into the split rows' dead V-third
    if (l < 16) {
      float* ml0 = (float*)&scratch[(size_t)(b * 2048 + qbase + l) * 3072 + 2048];
      ml0[h * 2 + (zone - 1)] = lsum[0];
      float* ml1 =
          (float*)&scratch[(size_t)(b * 2048 + qbase + 16 + l) * 3072 + 2048];
      ml1[h * 2 + (zone - 1)] = lsum[1];
    }
  }
}

// ---------------- merge split-KV partials for rows 1024..2047 ----------------
__global__ __launch_bounds__(256) void k_merge(const u16t* __restrict__ scratch,
                                               u16t* __restrict__ outp) {
  int x = blockIdx.x;
  int b = x >> 10, rr = x & 1023, row = 1024 + rr;
  int c4 = threadIdx.x * 4;
  int h = c4 >> 6;
  const float* ml = (const float*)&scratch[(size_t)(b * 2048 + row) * 3072 + 2048];
  float inv = 1.0f / (ml[h * 2] + ml[h * 2 + 1]);
  u16t* op = &outp[(size_t)(b * 2048 + row) * 1024 + c4];
  const u16t* o1 = &scratch[(size_t)(b * 2048 + rr) * 3072 + 2048 + c4];
  u16x4 a = *(const u16x4*)op;
  u16x4 bb = *(const u16x4*)o1;
  u16x4 o;
#pragma unroll
  for (int i = 0; i < 4; ++i) o[i] = f2bf((bf2f(a[i]) + bf2f(bb[i])) * inv);
  *(u16x4*)op = o;
}

extern "C" void kernel_launch(void* const* d_in, const int* in_sizes, int n_in,
                              void* d_out, int out_size, void* d_ws, size_t ws_size,
                              hipStream_t stream) {
  const float* x = (const float*)d_in[0];
  const float* wq = (const float*)d_in[1];
  const float* bq = (const float*)d_in[2];
  const float* wk = (const float*)d_in[3];
  const float* bk = (const float*)d_in[4];
  const float* wv = (const float*)d_in[5];
  const float* bv = (const float*)d_in[6];
  const float* wo = (const float*)d_in[7];
  const float* bo = (const float*)d_in[8];

  char* ws = (char*)d_ws;
  u16t* xb = (u16t*)ws;                    //  8 MB: x bf16 (later reused as attn_out)
  u16t* wqkvT = (u16t*)(ws + (8u << 20));  //  6 MB: [wq^T; wk^T; wv^T] bf16
  u16t* woT = (u16t*)(ws + (14u << 20));   //  2 MB: wo^T bf16
  u16t* qkv = (u16t*)(ws + (16u << 20));   // 24 MB: [4096][3072] bf16; V-third = scratch
  u16t* vt = (u16t*)(ws + (40u << 20));    //  8 MB: [32][64][2048] bf16
  u16t* attn_out = xb;

  k_convert_x<<<4096, 256, 0, stream>>>(x, xb);
  k_transw<<<dim3(16, 16, 4), 256, 0, stream>>>(wq, wk, wv, wo, wqkvT, woT);
  k_gemm_bt<2, true, true><<<dim3(64, 24), 256, 0, stream>>>(
      xb, wqkvT, qkv, bq, bk, bv, vt, 4096, 3072, 1024);
  k_attn<<<dim3(32, 24), 256, 0, stream>>>(qkv, vt, attn_out, qkv);
  k_merge<<<2048, 256, 0, stream>>>(qkv, attn_out);
  k_gemm_bt<2, false, false><<<dim3(64, 8), 256, 0, stream>>>(
      attn_out, woT, d_out, bo, bo, bo, nullptr, 4096, 1024, 1024);
}

// Round 18
// 104.918 us; speedup vs baseline: 1.1251x; 1.1251x over previous
//
#include <hip/hip_runtime.h>
#include <hip/hip_bf16.h>
#include <cstdint>

#define DEV static __device__ __forceinline__

typedef unsigned short u16t;
typedef __attribute__((ext_vector_type(4))) float f32x4;
typedef __attribute__((ext_vector_type(4))) unsigned short u16x4;
typedef __attribute__((ext_vector_type(8))) unsigned short u16x8;
typedef __attribute__((ext_vector_type(8))) __bf16 bf16x8;

DEV u16t f2bf(float f) {
  unsigned u = __builtin_bit_cast(unsigned, f);
  u += 0x7fffu + ((u >> 16) & 1u);
  return (u16t)(u >> 16);
}
DEV float bf2f(u16t h) {
  unsigned u = ((unsigned)h) << 16;
  return __builtin_bit_cast(float, u);
}

DEV void gload_lds16(const void* g, void* l) {
  __builtin_amdgcn_global_load_lds(
      (const __attribute__((address_space(1))) void*)g,
      (__attribute__((address_space(3))) void*)l, 16, 0, 0);
}

DEV bf16x8 ldsfrag(const u16t* p) {
  return __builtin_bit_cast(bf16x8, *(const u16x8*)p);
}

// raw workgroup barrier WITHOUT __syncthreads' implicit vmcnt(0) drain
DEV void bsync() {
  asm volatile("" ::: "memory");
  __builtin_amdgcn_s_barrier();
  asm volatile("" ::: "memory");
}

// -------- fused preprocessing: weight transpose+convert AND x convert --------
// flat grid 5120 x 256: blocks 0..1023 transpose the 4 weight matrices
// (fp32 [K][N] -> bf16 [N][K]); blocks 1024..5119 convert x (fp32 -> bf16).
__global__ __launch_bounds__(256) void k_prep(const float* __restrict__ x,
                                              const float* __restrict__ w0,
                                              const float* __restrict__ w1,
                                              const float* __restrict__ w2,
                                              const float* __restrict__ w3,
                                              u16t* __restrict__ xb,
                                              u16t* __restrict__ qkvT,
                                              u16t* __restrict__ oT) {
  __shared__ float lds[64][68];
  const int bx = blockIdx.x;
  const int t = threadIdx.x;
  if (bx >= 1024) {
    int i = ((bx - 1024) * 256 + t) * 4;
    f32x4 v = *(const f32x4*)&x[i];
    u16x4 o;
#pragma unroll
    for (int j = 0; j < 4; ++j) o[j] = f2bf(v[j]);
    *(u16x4*)&xb[i] = o;
    return;
  }
  const int z = bx >> 8, rem = bx & 255;
  const float* W = (z == 0) ? w0 : (z == 1) ? w1 : (z == 2) ? w2 : w3;
  u16t* OUT = (z < 3) ? (qkvT + (size_t)z * 1024 * 1024) : oT;
  int k0 = (rem >> 4) * 64, n0 = (rem & 15) * 64;
  int kl = t >> 4, n4 = (t & 15) << 2;
#pragma unroll
  for (int p = 0; p < 4; ++p) {
    f32x4 v = *(const f32x4*)&W[(size_t)(k0 + kl + p * 16) * 1024 + n0 + n4];
    *(f32x4*)&lds[kl + p * 16][n4] = v;
  }
  __syncthreads();
  int nl = t >> 4, k4 = (t & 15) << 2;
#pragma unroll
  for (int p = 0; p < 4; ++p) {
    int n = nl + p * 16;
    u16x4 o;
#pragma unroll
    for (int i = 0; i < 4; ++i) o[i] = f2bf(lds[k4 + i][n]);
    *(u16x4*)&OUT[(size_t)(n0 + n) * 1024 + k0 + k4] = o;
  }
}

// ---------------- GEMM: C[M,N] = A[M,K] * BT[N,K]^T + bias ----------------
// m-tile = MI*32 rows, n-tile = 128. 2-phase counted-vmcnt double-buffer
// (r7/r13/r14-proven). VSPLIT: cols >= 2048 written transposed into vt[bh][d][s].
template <int MI, bool BF16_OUT, bool VSPLIT>
__global__ __launch_bounds__(256) void k_gemm_bt(const u16t* __restrict__ A,
                                                 const u16t* __restrict__ BT,
                                                 void* __restrict__ Cout,
                                                 const float* __restrict__ b0,
                                                 const float* __restrict__ b1,
                                                 const float* __restrict__ b2,
                                                 u16t* __restrict__ vt,
                                                 int M, int N, int K) {
  __shared__ u16t Al[2][MI * 32 * 64];
  __shared__ u16t Bl[2][128 * 64];
  const int tid = threadIdx.x;
  const int l = tid & 63;
  const int w = tid >> 6;
  const int m0 = blockIdx.x * (MI * 32), n0 = blockIdx.y * 128;
  const int wm = (w >> 1) * (MI * 16), wn = (w & 1) * 64;
  const int lm = l & 15, lh = l >> 4;
  f32x4 acc[MI][4] = {};

  auto stage = [&](int bb, int t) {
    const int k0 = t << 6;
#pragma unroll
    for (int s = 0; s < MI; ++s) {
      int c = s * 256 + tid;
      int row = c >> 3, slot = c & 7;
      int ks = k0 + (((slot ^ (row & 7)) & 7) << 3);
      gload_lds16(A + (size_t)(m0 + row) * K + ks, &Al[bb][c * 8]);
    }
#pragma unroll
    for (int s = 0; s < 4; ++s) {
      int c = s * 256 + tid;
      int row = c >> 3, slot = c & 7;
      int ks = k0 + (((slot ^ (row & 7)) & 7) << 3);
      gload_lds16(BT + (size_t)(n0 + row) * K + ks, &Bl[bb][c * 8]);
    }
  };

  const int nt = K >> 6;
  stage(0, 0);
  for (int t = 0; t < nt; ++t) {
    if (t + 1 < nt) {
      stage((t + 1) & 1, t + 1);
      if (MI == 2)
        asm volatile("s_waitcnt vmcnt(6)" ::: "memory");
      else
        asm volatile("s_waitcnt vmcnt(8)" ::: "memory");
    } else {
      asm volatile("s_waitcnt vmcnt(0)" ::: "memory");
    }
    bsync();
    const int buf = t & 1;

#pragma unroll
    for (int kk = 0; kk < 2; ++kk) {
      bf16x8 af[MI], bfr[4];
#pragma unroll
      for (int i = 0; i < MI; ++i) {
        int ra = wm + i * 16 + lm;
        int sa = (kk * 4 + lh) ^ (ra & 7);
        af[i] = ldsfrag(&Al[buf][ra * 64 + sa * 8]);
      }
#pragma unroll
      for (int i = 0; i < 4; ++i) {
        int rb = wn + i * 16 + lm;
        int sb = (kk * 4 + lh) ^ (rb & 7);
        bfr[i] = ldsfrag(&Bl[buf][rb * 64 + sb * 8]);
      }
#pragma unroll
      for (int i = 0; i < MI; ++i)
#pragma unroll
        for (int j = 0; j < 4; ++j)
          acc[i][j] = __builtin_amdgcn_mfma_f32_16x16x32_bf16(af[i], bfr[j],
                                                              acc[i][j], 0, 0, 0);
    }
    bsync();
  }

  if (!VSPLIT || (n0 + wn) < 2048) {
#pragma unroll
    for (int i = 0; i < MI; ++i) {
      int row = m0 + wm + i * 16 + (lh << 2);
#pragma unroll
      for (int j = 0; j < 4; ++j) {
        int col = n0 + wn + j * 16 + lm;
        const float* bp = (col < 1024) ? b0 : ((col < 2048) ? b1 : b2);
        float bias = bp[col & 1023];
#pragma unroll
        for (int r = 0; r < 4; ++r) {
          float v = acc[i][j][r] + bias;
          if (BF16_OUT)
            ((u16t*)Cout)[(size_t)(row + r) * N + col] = f2bf(v);
          else
            ((float*)Cout)[(size_t)(row + r) * N + col] = v;
        }
      }
    }
  } else {
    // V projection: write transposed to vt[(b*16+h)*64 + d][s]
#pragma unroll
    for (int i = 0; i < MI; ++i) {
      int row = m0 + wm + i * 16 + (lh << 2);
      int bidx = row >> 11, s0 = row & 2047;
#pragma unroll
      for (int j = 0; j < 4; ++j) {
        int col = n0 + wn + j * 16 + lm;
        int d = col - 2048;
        int hh = d >> 6, dd = d & 63;
        float bias = b2[d];
        u16x4 o;
#pragma unroll
        for (int r = 0; r < 4; ++r) o[r] = f2bf(acc[i][j][r] + bias);
        *(u16x4*)&vt[((size_t)((bidx * 16 + hh) * 64 + dd)) * 2048 + s0] = o;
      }
    }
  }
}

// ---------------- causal flash attention (split-KV + 32 q-rows/wave, r14-proven) ----------------
__global__ __launch_bounds__(256, 2) void k_attn(const u16t* qkv,
                                                 const u16t* __restrict__ vt,
                                                 u16t* __restrict__ outp,
                                                 u16t* scratch) {
  __shared__ u16t Kl[4096];        // [kv=64][d=64], 16B-slot swizzled
  __shared__ u16t Vl[4096];        // [d=64][kv=64], 16B-slot swizzled
  __shared__ u16t Pl[4][2][1024];  // [wave][qm][q=16][kv=64], swizzled
  const int tid = threadIdx.x, l = tid & 63, w = tid >> 6;
  const int lm = l & 15, lh = l >> 4;
  const int bh = blockIdx.x, b = bh >> 4, h = bh & 15;
  const int y = blockIdx.y;
  const int zone = y >> 3, j = y & 7;
  const int qt = (zone == 0) ? j : (15 - j);  // 128-row q-tile index
  const int q0 = qt * 128;
  const int halfn = qt + 1;
  const int t0 = (zone == 2) ? halfn : 0;
  const int t1 = (zone == 1) ? halfn : (2 * qt + 2);
  const int qbase = q0 + w * 32;

  // Q fragments (B-operand), pre-scaled by (1/sqrt(64))*log2(e) -> exp2 softmax
  bf16x8 aq[2][2];
#pragma unroll
  for (int qm = 0; qm < 2; ++qm)
#pragma unroll
    for (int kk = 0; kk < 2; ++kk) {
      const u16t* src = qkv + (size_t)(b * 2048 + qbase + qm * 16 + lm) * 3072 +
                        h * 64 + kk * 32 + lh * 8;
      u16x8 v = *(const u16x8*)src;
      u16x8 o;
#pragma unroll
      for (int e = 0; e < 8; ++e) o[e] = f2bf(bf2f(v[e]) * 0.1803368801f);
      aq[qm][kk] = __builtin_bit_cast(bf16x8, o);
    }

  float lsum[2] = {0.f, 0.f};
  f32x4 aco[2][4] = {};
  const int qr0 = qbase + lm, qr1 = qbase + 16 + lm;

  const u16t* Kg = qkv + (size_t)b * 2048 * 3072 + 1024 + h * 64;
  const u16t* Vg = vt + (size_t)bh * 64 * 2048;

  auto stage = [&](int t) {
#pragma unroll
    for (int s = 0; s < 2; ++s) {
      int c = s * 256 + tid;
      int row = c >> 3, col = ((c & 7) ^ (row & 7)) << 3;
      gload_lds16(Kg + (size_t)(t * 64 + row) * 3072 + col, &Kl[c * 8]);
    }
#pragma unroll
    for (int s = 0; s < 2; ++s) {
      int c = s * 256 + tid;
      int row = c >> 3, col = ((c & 7) ^ (row & 7)) << 3;
      gload_lds16(Vg + (size_t)row * 2048 + t * 64 + col, &Vl[c * 8]);
    }
  };

  for (int t = t0; t < t1; ++t) {
    stage(t);
    asm volatile("s_waitcnt vmcnt(0)" ::: "memory");
    bsync();

    // wave-uniform: skip fully-masked diagonal tiles (kv all > every q-row)
    if (t * 64 <= qbase + 31) {
      // S^T = K * Q
      f32x4 accs[2][4] = {};
#pragma unroll
      for (int kk = 0; kk < 2; ++kk) {
        bf16x8 ak[4];
#pragma unroll
        for (int nk = 0; nk < 4; ++nk) {
          int rk = nk * 16 + lm;
          int s16 = (kk * 4 + lh) ^ (rk & 7);
          ak[nk] = ldsfrag(&Kl[rk * 64 + s16 * 8]);
        }
        __builtin_amdgcn_s_setprio(1);
#pragma unroll
        for (int nk = 0; nk < 4; ++nk) {
          accs[0][nk] = __builtin_amdgcn_mfma_f32_16x16x32_bf16(
              ak[nk], aq[0][kk], accs[0][nk], 0, 0, 0);
          accs[1][nk] = __builtin_amdgcn_mfma_f32_16x16x32_bf16(
              ak[nk], aq[1][kk], accs[1][nk], 0, 0, 0);
        }
        __builtin_amdgcn_s_setprio(0);
      }

      // causal mask only when this wave's rows touch the diagonal (wave-uniform)
      if (t * 64 + 63 > qbase) {
#pragma unroll
        for (int nk = 0; nk < 4; ++nk)
#pragma unroll
          for (int r = 0; r < 4; ++r) {
            int kvpos = t * 64 + nk * 16 + lh * 4 + r;
            if (kvpos > qr0) accs[0][nk][r] = -1e30f;
            if (kvpos > qr1) accs[1][nk][r] = -1e30f;
          }
      }

      // p = exp2(s'); partial lsum; cvt_pk pack -> b64 store to P-LDS
#pragma unroll
      for (int qm = 0; qm < 2; ++qm) {
        u16t* Pw = &Pl[w][qm][0];
#pragma unroll
        for (int nk = 0; nk < 4; ++nk) {
          float p0 = exp2f(accs[qm][nk][0]);
          float p1 = exp2f(accs[qm][nk][1]);
          float p2 = exp2f(accs[qm][nk][2]);
          float p3 = exp2f(accs[qm][nk][3]);
          lsum[qm] += (p0 + p1) + (p2 + p3);
          unsigned wlo, whi;
          asm("v_cvt_pk_bf16_f32 %0, %1, %2" : "=v"(wlo) : "v"(p0), "v"(p1));
          asm("v_cvt_pk_bf16_f32 %0, %1, %2" : "=v"(whi) : "v"(p2), "v"(p3));
          int off = lm * 64 + ((((2 * nk + (lh >> 1)) ^ (lm & 7)) & 7) << 3) +
                    ((lh & 1) << 2);
          *(uint2*)&Pw[off] = make_uint2(wlo, whi);
        }
      }

      // O += P * V
#pragma unroll
      for (int kk = 0; kk < 2; ++kk) {
        int sp = (kk * 4 + lh) ^ (lm & 7);
        bf16x8 ap0 = ldsfrag(&Pl[w][0][lm * 64 + sp * 8]);
        bf16x8 ap1 = ldsfrag(&Pl[w][1][lm * 64 + sp * 8]);
        __builtin_amdgcn_s_setprio(1);
#pragma unroll
        for (int nd = 0; nd < 4; ++nd) {
          int rv = nd * 16 + lm;
          int sv = (kk * 4 + lh) ^ (rv & 7);
          bf16x8 bv = ldsfrag(&Vl[rv * 64 + sv * 8]);
          aco[0][nd] =
              __builtin_amdgcn_mfma_f32_16x16x32_bf16(ap0, bv, aco[0][nd], 0, 0, 0);
          aco[1][nd] =
              __builtin_amdgcn_mfma_f32_16x16x32_bf16(ap1, bv, aco[1][nd], 0, 0, 0);
        }
        __builtin_amdgcn_s_setprio(0);
      }
    }

    bsync();
  }

  // epilogue: finish lsum reduce over lh groups
#pragma unroll
  for (int qm = 0; qm < 2; ++qm) {
    lsum[qm] += __shfl_xor(lsum[qm], 16);
    lsum[qm] += __shfl_xor(lsum[qm], 32);
  }

  if (zone == 0) {
#pragma unroll
    for (int qm = 0; qm < 2; ++qm) {
      float inv = 1.0f / lsum[qm];
#pragma unroll
      for (int r = 0; r < 4; ++r) {
        float ir = __shfl(inv, lh * 4 + r);
        int row = qbase + qm * 16 + lh * 4 + r;
#pragma unroll
        for (int nd = 0; nd < 4; ++nd) {
          int col = h * 64 + nd * 16 + lm;
          outp[(size_t)(b * 2048 + row) * 1024 + col] = f2bf(aco[qm][nd][r] * ir);
        }
      }
    }
  } else {
    // store unnormalized partial O (bf16)
#pragma unroll
    for (int qm = 0; qm < 2; ++qm)
#pragma unroll
      for (int r = 0; r < 4; ++r) {
        int row = qbase + qm * 16 + lh * 4 + r;
#pragma unroll
        for (int nd = 0; nd < 4; ++nd) {
          int col = nd * 16 + lm;
          u16t v = f2bf(aco[qm][nd][r]);
          if (zone == 1)
            outp[(size_t)(b * 2048 + row) * 1024 + h * 64 + col] = v;
          else
            scratch[(size_t)(b * 2048 + row - 1024) * 3072 + 2048 + h * 64 + col] = v;
        }
      }
    // store partial l (f32) into the split rows' dead V-third
    if (l < 16) {
      float* ml0 = (float*)&scratch[(size_t)(b * 2048 + qbase + l) * 3072 + 2048];
      ml0[h * 2 + (zone - 1)] = lsum[0];
      float* ml1 =
          (float*)&scratch[(size_t)(b * 2048 + qbase + 16 + l) * 3072 + 2048];
      ml1[h * 2 + (zone - 1)] = lsum[1];
    }
  }
}

// ---------------- merge split-KV partials for rows 1024..2047 ----------------
__global__ __launch_bounds__(256) void k_merge(const u16t* __restrict__ scratch,
                                               u16t* __restrict__ outp) {
  int x = blockIdx.x;
  int b = x >> 10, rr = x & 1023, row = 1024 + rr;
  int c4 = threadIdx.x * 4;
  int h = c4 >> 6;
  const float* ml = (const float*)&scratch[(size_t)(b * 2048 + row) * 3072 + 2048];
  float inv = 1.0f / (ml[h * 2] + ml[h * 2 + 1]);
  u16t* op = &outp[(size_t)(b * 2048 + row) * 1024 + c4];
  const u16t* o1 = &scratch[(size_t)(b * 2048 + rr) * 3072 + 2048 + c4];
  u16x4 a = *(const u16x4*)op;
  u16x4 bb = *(const u16x4*)o1;
  u16x4 o;
#pragma unroll
  for (int i = 0; i < 4; ++i) o[i] = f2bf((bf2f(a[i]) + bf2f(bb[i])) * inv);
  *(u16x4*)op = o;
}

extern "C" void kernel_launch(void* const* d_in, const int* in_sizes, int n_in,
                              void* d_out, int out_size, void* d_ws, size_t ws_size,
                              hipStream_t stream) {
  const float* x = (const float*)d_in[0];
  const float* wq = (const float*)d_in[1];
  const float* bq = (const float*)d_in[2];
  const float* wk = (const float*)d_in[3];
  const float* bk = (const float*)d_in[4];
  const float* wv = (const float*)d_in[5];
  const float* bv = (const float*)d_in[6];
  const float* wo = (const float*)d_in[7];
  const float* bo = (const float*)d_in[8];

  char* ws = (char*)d_ws;
  u16t* xb = (u16t*)ws;                    //  8 MB: x bf16 (later reused as attn_out)
  u16t* wqkvT = (u16t*)(ws + (8u << 20));  //  6 MB: [wq^T; wk^T; wv^T] bf16
  u16t* woT = (u16t*)(ws + (14u << 20));   //  2 MB: wo^T bf16
  u16t* qkv = (u16t*)(ws + (16u << 20));   // 24 MB: [4096][3072] bf16; V-third = scratch
  u16t* vt = (u16t*)(ws + (40u << 20));    //  8 MB: [32][64][2048] bf16
  u16t* attn_out = xb;

  k_prep<<<5120, 256, 0, stream>>>(x, wq, wk, wv, wo, xb, wqkvT, woT);
  k_gemm_bt<2, true, true><<<dim3(64, 24), 256, 0, stream>>>(
      xb, wqkvT, qkv, bq, bk, bv, vt, 4096, 3072, 1024);
  k_attn<<<dim3(32, 24), 256, 0, stream>>>(qkv, vt, attn_out, qkv);
  k_merge<<<2048, 256, 0, stream>>>(qkv, attn_out);
  k_gemm_bt<2, false, false><<<dim3(64, 8), 256, 0, stream>>>(
      attn_out, woT, d_out, bo, bo, bo, nullptr, 4096, 1024, 1024);
}